// Round 4
// baseline (1259.134 us; speedup 1.0000x reference)
//
#include <hip/hip_runtime.h>
#include <hip/hip_bf16.h>

#define M_DIM 16384
#define N_DIM 8192
#define K_DIM 4096
#define NT (K_DIM / 64)  // 64 K-tiles, 32 groups of 2

typedef __attribute__((ext_vector_type(4))) float f32x4;
typedef __attribute__((ext_vector_type(8))) __bf16 bf16x8;
typedef __attribute__((ext_vector_type(4))) unsigned short u16x4;

static __device__ __forceinline__ unsigned short f2bf(float f) {
  __bf16 h = (__bf16)f;
  return __builtin_bit_cast(unsigned short, h);
}

static __device__ __forceinline__ void gl_lds16(const unsigned short* g, unsigned short* l) {
  __builtin_amdgcn_global_load_lds(
      (const __attribute__((address_space(1))) unsigned int*)g,
      (__attribute__((address_space(3))) unsigned int*)l, 16, 0, 0);
}

// ---- prep: A [M][K] f32 -> bf16 (same layout) ----
__global__ void k_convert_a(const float* __restrict__ a, unsigned short* __restrict__ o) {
  const size_t n8 = (size_t)M_DIM * K_DIM / 8;
  for (size_t i = (size_t)blockIdx.x * blockDim.x + threadIdx.x; i < n8;
       i += (size_t)gridDim.x * blockDim.x) {
    const f32x4* p = (const f32x4*)(a + i * 8);
    f32x4 v0 = p[0];
    f32x4 v1 = p[1];
    u16x4 r0, r1;
#pragma unroll
    for (int j = 0; j < 4; ++j) { r0[j] = f2bf(v0[j]); r1[j] = f2bf(v1[j]); }
    *(u16x4*)(o + i * 8) = r0;
    *(u16x4*)(o + i * 8 + 4) = r1;
  }
}

// ---- prep: W [K][N] f32 -> Wt [N][K] bf16 (transpose + convert) ----
__global__ void k_convert_w_t(const float* __restrict__ w, unsigned short* __restrict__ wt) {
  __shared__ float tile[64][65];
  const int bk = blockIdx.y * 64;
  const int bn = blockIdx.x * 64;
  const int t = threadIdx.x;  // 256
  const int c4 = (t & 15) * 4;
  const int r = t >> 4;
#pragma unroll
  for (int p = 0; p < 4; ++p) {
    const int row = r + p * 16;
    f32x4 v = *(const f32x4*)&w[(size_t)(bk + row) * N_DIM + bn + c4];
    tile[row][c4 + 0] = v[0];
    tile[row][c4 + 1] = v[1];
    tile[row][c4 + 2] = v[2];
    tile[row][c4 + 3] = v[3];
  }
  __syncthreads();
#pragma unroll
  for (int p = 0; p < 4; ++p) {
    const int c = r + p * 16;
    u16x4 o;
#pragma unroll
    for (int j = 0; j < 4; ++j) o[j] = f2bf(tile[c4 + j][c]);
    *(u16x4*)&wt[(size_t)(bn + c) * K_DIM + bk + c4] = o;
  }
}

// ---- main GEMM: 256x256 tile, BK=64, 8-phase / 2-K-tile, K-HALF LDS regions ----
// LDS 128KB = 2 tile-buffers x {Ak0,Ak1,Bk0,Bk1} x 16KB (256 rows x 32 k).
// Phases per tile: (kk0,mL) (kk0,mH) (kk1,mL) (kk1,mH) -> reads 8/4/8/4.
// Stage slots (group it, u=2it, v=u+1):
//   ph0:Ak1(v) ph1:Bk1(v) ph2:Ak0(u+2) ph3:Bk0(u+2)
//   ph4:Ak1(u+2) ph5:Bk1(u+2) ph6:Ak0(v+2) ph7:Bk0(v+2)
// Drain vmcnt(8) at end of every odd phase: drained stages >= 4 phases old.
// WAR: each region staged >=1 barrier after its previous tenant's last read.
// Swizzle: phys granule = g ^ (row&3) within 32-elem rows (both sides).
__global__ __launch_bounds__(512, 2) void k_gemm_8ph(
    const unsigned short* __restrict__ A, const unsigned short* __restrict__ Bt,
    const float* __restrict__ bias, float* __restrict__ C) {
  __shared__ __align__(16) unsigned short S[65536];  // 128 KB

  const int tid = threadIdx.x;
  const int lane = tid & 63;
  const int wave = tid >> 6;  // 0..7
  const int wm = wave >> 2;   // 0..1 -> 128-row half
  const int wn = wave & 3;    // 0..3 -> 64-col block
  const int fr = lane & 15;
  const int hi = lane >> 4;   // 0..3

  // T1: XCD-aware bijective swizzle (2048 blocks, %8==0)
  const int bid = blockIdx.x;
  const int swz = (bid & 7) * 256 + (bid >> 3);
  const int local = swz & 255;
  const int tm = local & 63;
  const int tn = (swz >> 8) * 4 + (local >> 6);
  const int brow = tm * 256;
  const int bcol = tn * 256;

  // staging source: thread -> (row = tid>>2 [+128 for 2nd call], granule tid&3)
  const int srow2 = tid >> 2;                              // 0..127
  const int sgel = ((tid & 3) ^ (srow2 & 3)) * 8;          // swizzled source granule
  const unsigned short* aS = A + (size_t)(brow + srow2) * K_DIM + sgel;
  const unsigned short* bS = Bt + (size_t)(bcol + srow2) * K_DIM + sgel;

#define STG(reg, srcp, tt, kh)                                        \
  do {                                                                \
    unsigned short* d_ = S + ((tt)&1) * 32768 + (reg) + tid * 8;      \
    const unsigned short* g_ = (srcp) + (size_t)(tt)*64 + (kh)*32;    \
    gl_lds16(g_, d_);                                                 \
    gl_lds16(g_ + (size_t)128 * K_DIM, d_ + 4096);                    \
  } while (0)

  // frag-read swizzled granule offset (elements within 32-elem row)
  const int swk = ((hi ^ (fr & 3)) * 8);
  const unsigned short* SA = S + (wm * 128 + fr) * 32 + swk;          // + X*32768 + h*8192 + (mb+m*16)*32
  const unsigned short* SB = S + 16384 + (wn * 64 + fr) * 32 + swk;   // + X*32768 + h*8192 + n*512

#define RD_A(dst, X, h, mb)                                                       \
  _Pragma("unroll") for (int m_ = 0; m_ < 4; ++m_)                                \
      dst[m_] = *(const bf16x8*)(SA + (X)*32768 + (h)*8192 + ((mb) + m_ * 16) * 32);
#define RD_B(dst, X, h)                                                           \
  _Pragma("unroll") for (int n_ = 0; n_ < 4; ++n_)                                \
      dst[n_] = *(const bf16x8*)(SB + (X)*32768 + (h)*8192 + n_ * 512);

  f32x4 acc[8][4] = {};

#define BAR __builtin_amdgcn_s_barrier()
#define LGKM0 asm volatile("s_waitcnt lgkmcnt(0)" ::: "memory")
#define SCHED0 __builtin_amdgcn_sched_barrier(0)
#define VMC(n) asm volatile("s_waitcnt vmcnt(" #n ")" ::: "memory")
#define MFMA16(AV, MB, BV)                                                            \
  __builtin_amdgcn_s_setprio(1);                                                      \
  _Pragma("unroll") for (int m_ = 0; m_ < 4; ++m_)                                    \
      _Pragma("unroll") for (int n_ = 0; n_ < 4; ++n_)                                \
          acc[(MB) + m_][n_] = __builtin_amdgcn_mfma_f32_16x16x32_bf16(               \
              AV[m_], BV[n_], acc[(MB) + m_][n_], 0, 0, 0);                           \
  __builtin_amdgcn_s_setprio(0)

  // ---- prologue: tile0 all 4 regions + {Ak0,Bk0} of tile1; drain tile0 k0 pair ----
  STG(0, aS, 0, 0);      // Ak0(0)
  STG(16384, bS, 0, 0);  // Bk0(0)
  STG(8192, aS, 0, 1);   // Ak1(0)
  STG(24576, bS, 0, 1);  // Bk1(0)
  STG(0, aS, 1, 0);      // Ak0(1)
  STG(16384, bS, 1, 0);  // Bk0(1)
  VMC(8);                // drains Ak0(0),Bk0(0); leaves 4 stages (8 loads)
  BAR;

  const int NTH = NT / 2;
  for (int it = 0; it < NTH; ++it) {
    const int u = 2 * it, v = u + 1;
    const bool pf = (it < NTH - 1);
    bf16x8 aL[4], aH[4], bA[4], bB[4];

    // ---- ph0: u kk0 mL (8 reads); stage Ak1(v) ----
    RD_A(aL, 0, 0, 0); RD_B(bA, 0, 0);
    STG(8192, aS, v, 1);
    BAR; LGKM0; SCHED0;
    MFMA16(aL, 0, bA);
    BAR;

    // ---- ph1: u kk0 mH (4 reads); stage Bk1(v); drain ----
    RD_A(aH, 0, 0, 64);
    STG(24576, bS, v, 1);
    BAR; LGKM0; SCHED0;
    MFMA16(aH, 4, bA);
    VMC(8);  // drains Ak1(u),Bk1(u) (staged 4+ phases ago)
    BAR;

    // ---- ph2: u kk1 mL (8 reads); stage Ak0(u+2) ----
    RD_A(aL, 0, 1, 0); RD_B(bB, 0, 1);
    if (pf) STG(0, aS, u + 2, 0);
    BAR; LGKM0; SCHED0;
    MFMA16(aL, 0, bB);
    BAR;

    // ---- ph3: u kk1 mH (4 reads); stage Bk0(u+2); drain ----
    RD_A(aH, 0, 1, 64);
    if (pf) STG(16384, bS, u + 2, 0);
    BAR; LGKM0; SCHED0;
    MFMA16(aH, 4, bB);
    if (pf) { VMC(8); } else { VMC(4); }  // drains Ak0(v),Bk0(v)
    BAR;

    // ---- ph4: v kk0 mL (8 reads); stage Ak1(u+2) ----
    RD_A(aL, 1, 0, 0); RD_B(bA, 1, 0);
    if (pf) STG(8192, aS, u + 2, 1);
    BAR; LGKM0; SCHED0;
    MFMA16(aL, 0, bA);
    BAR;

    // ---- ph5: v kk0 mH (4 reads); stage Bk1(u+2); drain ----
    RD_A(aH, 1, 0, 64);
    if (pf) STG(24576, bS, u + 2, 1);
    BAR; LGKM0; SCHED0;
    MFMA16(aH, 4, bA);
    if (pf) { VMC(8); } else { VMC(0); }  // drains Ak1(v),Bk1(v)
    BAR;

    // ---- ph6: v kk1 mL (8 reads); stage Ak0(v+2) ----
    RD_A(aL, 1, 1, 0); RD_B(bB, 1, 1);
    if (pf) STG(0, aS, v + 2, 0);
    BAR; LGKM0; SCHED0;
    MFMA16(aL, 0, bB);
    BAR;

    // ---- ph7: v kk1 mH (4 reads); stage Bk0(v+2); drain ----
    RD_A(aH, 1, 1, 64);
    if (pf) STG(16384, bS, v + 2, 0);
    BAR; LGKM0; SCHED0;
    MFMA16(aH, 4, bB);
    if (pf) { VMC(8); }  // drains Ak0(u+2),Bk0(u+2)
    BAR;
  }
#undef STG
#undef RD_A
#undef RD_B
#undef MFMA16
#undef BAR
#undef LGKM0
#undef SCHED0
#undef VMC

  // ---- epilogue: C/D layout col = lane&15, row = (lane>>4)*4 + j ----
#pragma unroll
  for (int n = 0; n < 4; ++n) {
    const int col = bcol + wn * 64 + n * 16 + fr;
    const float bb = bias[col];
#pragma unroll
    for (int m = 0; m < 8; ++m) {
      const int row0 = brow + wm * 128 + m * 16 + hi * 4;
#pragma unroll
      for (int j = 0; j < 4; ++j)
        C[(size_t)(row0 + j) * N_DIM + col] = acc[m][n][j] + bb;
    }
  }
}

// ---- fallback (only if ws too small): fp32 LDS-tiled GEMM ----
__global__ __launch_bounds__(256) void k_gemm_f32(
    const float* __restrict__ A, const float* __restrict__ W,
    const float* __restrict__ bias, float* __restrict__ C) {
  __shared__ float As[64][17];
  __shared__ float Ws[16][64];
  const int tid = threadIdx.x;
  const int tx = tid & 15, ty = tid >> 4;
  const int brow = blockIdx.y * 64, bcol = blockIdx.x * 64;
  float acc[4][4] = {};
  for (int ks = 0; ks < K_DIM; ks += 16) {
    {
      const int m = tid >> 2, k = (tid & 3) * 4;
      f32x4 v = *(const f32x4*)&A[(size_t)(brow + m) * K_DIM + ks + k];
      As[m][k] = v[0]; As[m][k + 1] = v[1]; As[m][k + 2] = v[2]; As[m][k + 3] = v[3];
    }
    {
      const int k = tid >> 4, n = (tid & 15) * 4;
      *(f32x4*)&Ws[k][n] = *(const f32x4*)&W[(size_t)(ks + k) * N_DIM + bcol + n];
    }
    __syncthreads();
#pragma unroll
    for (int k = 0; k < 16; ++k) {
      float av[4], bv[4];
#pragma unroll
      for (int i = 0; i < 4; ++i) av[i] = As[ty * 4 + i][k];
#pragma unroll
      for (int j = 0; j < 4; ++j) bv[j] = Ws[k][tx * 4 + j];
#pragma unroll
      for (int i = 0; i < 4; ++i)
#pragma unroll
        for (int j = 0; j < 4; ++j) acc[i][j] += av[i] * bv[j];
    }
    __syncthreads();
  }
#pragma unroll
  for (int i = 0; i < 4; ++i) {
    const int row = brow + ty * 4 + i;
#pragma unroll
    for (int j = 0; j < 4; ++j) {
      const int col = bcol + tx * 4 + j;
      C[(size_t)row * N_DIM + col] = acc[i][j] + bias[col];
    }
  }
}

extern "C" void kernel_launch(void* const* d_in, const int* in_sizes, int n_in,
                              void* d_out, int out_size, void* d_ws, size_t ws_size,
                              hipStream_t stream) {
  const float* inp = (const float*)d_in[0];   // [16384, 4096]
  const float* w = (const float*)d_in[1];     // [4096, 8192]
  const float* bias = (const float*)d_in[2];  // [8192]
  float* out = (float*)d_out;                 // [16384, 8192]

  const size_t needA = (size_t)M_DIM * K_DIM * sizeof(unsigned short);  // 128 MB
  const size_t needW = (size_t)N_DIM * K_DIM * sizeof(unsigned short);  // 64 MB

  if (ws_size >= needA + needW) {
    unsigned short* Abf = (unsigned short*)d_ws;
    unsigned short* Wtb = (unsigned short*)((char*)d_ws + needA);
    k_convert_a<<<2048, 256, 0, stream>>>(inp, Abf);
    k_convert_w_t<<<dim3(N_DIM / 64, K_DIM / 64), 256, 0, stream>>>(w, Wtb);
    k_gemm_8ph<<<(M_DIM / 256) * (N_DIM / 256), 512, 0, stream>>>(Abf, Wtb, bias, out);
  } else {
    k_gemm_f32<<<dim3(N_DIM / 64, M_DIM / 64), 256, 0, stream>>>(inp, w, bias, out);
  }
}

// Round 5
// 1241.652 us; speedup vs baseline: 1.0141x; 1.0141x over previous
//
#include <hip/hip_runtime.h>
#include <hip/hip_bf16.h>

#define M_DIM 16384
#define N_DIM 8192
#define K_DIM 4096
#define NT (K_DIM / 64)  // 64 K-tiles, 32 groups of 2

typedef __attribute__((ext_vector_type(4))) float f32x4;
typedef __attribute__((ext_vector_type(8))) __bf16 bf16x8;
typedef __attribute__((ext_vector_type(4))) unsigned short u16x4;

static __device__ __forceinline__ unsigned short f2bf(float f) {
  __bf16 h = (__bf16)f;
  return __builtin_bit_cast(unsigned short, h);
}

static __device__ __forceinline__ void gl_lds16(const unsigned short* g, unsigned short* l) {
  __builtin_amdgcn_global_load_lds(
      (const __attribute__((address_space(1))) unsigned int*)g,
      (__attribute__((address_space(3))) unsigned int*)l, 16, 0, 0);
}

// ---- prep: A [M][K] f32 -> bf16 (same layout) ----
__global__ void k_convert_a(const float* __restrict__ a, unsigned short* __restrict__ o) {
  const size_t n8 = (size_t)M_DIM * K_DIM / 8;
  for (size_t i = (size_t)blockIdx.x * blockDim.x + threadIdx.x; i < n8;
       i += (size_t)gridDim.x * blockDim.x) {
    const f32x4* p = (const f32x4*)(a + i * 8);
    f32x4 v0 = p[0];
    f32x4 v1 = p[1];
    u16x4 r0, r1;
#pragma unroll
    for (int j = 0; j < 4; ++j) { r0[j] = f2bf(v0[j]); r1[j] = f2bf(v1[j]); }
    *(u16x4*)(o + i * 8) = r0;
    *(u16x4*)(o + i * 8 + 4) = r1;
  }
}

// ---- prep: W [K][N] f32 -> Wt [N][K] bf16 (transpose + convert) ----
__global__ void k_convert_w_t(const float* __restrict__ w, unsigned short* __restrict__ wt) {
  __shared__ float tile[64][65];
  const int bk = blockIdx.y * 64;
  const int bn = blockIdx.x * 64;
  const int t = threadIdx.x;  // 256
  const int c4 = (t & 15) * 4;
  const int r = t >> 4;
#pragma unroll
  for (int p = 0; p < 4; ++p) {
    const int row = r + p * 16;
    f32x4 v = *(const f32x4*)&w[(size_t)(bk + row) * N_DIM + bn + c4];
    tile[row][c4 + 0] = v[0];
    tile[row][c4 + 1] = v[1];
    tile[row][c4 + 2] = v[2];
    tile[row][c4 + 3] = v[3];
  }
  __syncthreads();
#pragma unroll
  for (int p = 0; p < 4; ++p) {
    const int c = r + p * 16;
    u16x4 o;
#pragma unroll
    for (int j = 0; j < 4; ++j) o[j] = f2bf(tile[c4 + j][c]);
    *(u16x4*)&wt[(size_t)(bn + c) * K_DIM + bk + c4] = o;
  }
}

// ---- main GEMM: 256x256 tile, BK=64, 8-phase / 2-K-tile, K-HALF LDS regions ----
// LDS 128KB = 2 tile-buffers x {Ak0,Ak1,Bk0,Bk1} x 16KB (256 rows x 32 k).
// Phases per tile: (kk0,mL) (kk0,mH) (kk1,mL) (kk1,mH) -> reads 8/4/8/4.
// Stage slots: ph0:Ak1(v) ph1:Bk1(v) ph2:Ak0(u+2) ph3:Bk0(u+2)
//              ph4:Ak1(u+2) ph5:Bk1(u+2) ph6:Ak0(v+2) ph7:Bk0(v+2)
// vmcnt(8) at end of every odd phase: drained stages are 4 phases old.
// Swizzle: phys granule = g ^ ((row>>1)&3) within 32-elem rows (8 distinct
// 16B bank-quads per 8-lane group -> conflict-free; r4's row&3 gave 4 slots).
__global__ __launch_bounds__(512, 2) void k_gemm_8ph(
    const unsigned short* __restrict__ A, const unsigned short* __restrict__ Bt,
    const float* __restrict__ bias, float* __restrict__ C) {
  __shared__ __align__(16) unsigned short S[65536];  // 128 KB

  const int tid = threadIdx.x;
  const int lane = tid & 63;
  const int wave = tid >> 6;  // 0..7
  const int wm = wave >> 2;   // 0..1 -> 128-row half
  const int wn = wave & 3;    // 0..3 -> 64-col block
  const int fr = lane & 15;
  const int hi = lane >> 4;   // 0..3

  // T1: XCD-aware bijective swizzle (2048 blocks, %8==0)
  const int bid = blockIdx.x;
  const int swz = (bid & 7) * 256 + (bid >> 3);
  const int local = swz & 255;
  const int tm = local & 63;
  const int tn = (swz >> 8) * 4 + (local >> 6);
  const int brow = tm * 256;
  const int bcol = tn * 256;

  // staging source: thread -> row = tid>>2 (+128 for 2nd gl_lds), dest granule tid&3.
  // source granule = dest ^ s(row), s(row) = (row>>1)&3 = (tid>>3)&3 (both halves).
  const int srow2 = tid >> 2;                              // 0..127
  const int sgel = ((tid & 3) ^ ((tid >> 3) & 3)) * 8;     // swizzled source granule
  const unsigned short* aS = A + (size_t)(brow + srow2) * K_DIM + sgel;
  const unsigned short* bS = Bt + (size_t)(bcol + srow2) * K_DIM + sgel;

#define STG(reg, srcp, tt, kh)                                        \
  do {                                                                \
    unsigned short* d_ = S + ((tt)&1) * 32768 + (reg) + tid * 8;      \
    const unsigned short* g_ = (srcp) + (size_t)(tt)*64 + (kh)*32;    \
    gl_lds16(g_, d_);                                                 \
    gl_lds16(g_ + (size_t)128 * K_DIM, d_ + 4096);                    \
  } while (0)

  // frag-read swizzled granule: phys = hi ^ ((row>>1)&3), row bases mult of 16
  // so (row>>1)&3 == (fr>>1)&3 -> lane-constant, loop-invariant.
  const int swk = ((hi ^ ((fr >> 1) & 3)) * 8);
  const unsigned short* SA = S + (wm * 128 + fr) * 32 + swk;          // + X*32768 + h*8192 + (mb+m*16)*32
  const unsigned short* SB = S + 16384 + (wn * 64 + fr) * 32 + swk;   // + X*32768 + h*8192 + n*512

#define RD_A(dst, X, h, mb)                                                       \
  _Pragma("unroll") for (int m_ = 0; m_ < 4; ++m_)                                \
      dst[m_] = *(const bf16x8*)(SA + (X)*32768 + (h)*8192 + ((mb) + m_ * 16) * 32);
#define RD_B(dst, X, h)                                                           \
  _Pragma("unroll") for (int n_ = 0; n_ < 4; ++n_)                                \
      dst[n_] = *(const bf16x8*)(SB + (X)*32768 + (h)*8192 + n_ * 512);

  f32x4 acc[8][4] = {};

#define BAR __builtin_amdgcn_s_barrier()
#define LGKM0 asm volatile("s_waitcnt lgkmcnt(0)" ::: "memory")
#define SCHED0 __builtin_amdgcn_sched_barrier(0)
#define VMC(n) asm volatile("s_waitcnt vmcnt(" #n ")" ::: "memory")
#define MFMA16(AV, MB, BV)                                                            \
  __builtin_amdgcn_s_setprio(1);                                                      \
  _Pragma("unroll") for (int m_ = 0; m_ < 4; ++m_)                                    \
      _Pragma("unroll") for (int n_ = 0; n_ < 4; ++n_)                                \
          acc[(MB) + m_][n_] = __builtin_amdgcn_mfma_f32_16x16x32_bf16(               \
              AV[m_], BV[n_], acc[(MB) + m_][n_], 0, 0, 0);                           \
  __builtin_amdgcn_s_setprio(0)

  // ---- prologue: tile0 all 4 regions + {Ak0,Bk0} of tile1; drain tile0 k0 pair ----
  STG(0, aS, 0, 0);      // Ak0(0)
  STG(16384, bS, 0, 0);  // Bk0(0)
  STG(8192, aS, 0, 1);   // Ak1(0)
  STG(24576, bS, 0, 1);  // Bk1(0)
  STG(0, aS, 1, 0);      // Ak0(1)
  STG(16384, bS, 1, 0);  // Bk0(1)
  VMC(8);                // drains Ak0(0),Bk0(0); leaves 4 stages (8 loads)
  BAR;

  const int NTH = NT / 2;
  for (int it = 0; it < NTH; ++it) {
    const int u = 2 * it, v = u + 1;
    const bool pf = (it < NTH - 1);
    bf16x8 aL[4], aH[4], bA[4], bB[4];

    // ---- ph0: u kk0 mL (8 reads); stage Ak1(v) ----
    RD_A(aL, 0, 0, 0); RD_B(bA, 0, 0);
    STG(8192, aS, v, 1);
    BAR; LGKM0; SCHED0;
    MFMA16(aL, 0, bA);
    BAR;

    // ---- ph1: u kk0 mH (4 reads); stage Bk1(v); drain ----
    RD_A(aH, 0, 0, 64);
    STG(24576, bS, v, 1);
    BAR; LGKM0; SCHED0;
    MFMA16(aH, 4, bA);
    VMC(8);  // drains Ak1(u),Bk1(u) (4 phases old)
    BAR;

    // ---- ph2: u kk1 mL (8 reads); stage Ak0(u+2) ----
    RD_A(aL, 0, 1, 0); RD_B(bB, 0, 1);
    if (pf) STG(0, aS, u + 2, 0);
    BAR; LGKM0; SCHED0;
    MFMA16(aL, 0, bB);
    BAR;

    // ---- ph3: u kk1 mH (4 reads); stage Bk0(u+2); drain ----
    RD_A(aH, 0, 1, 64);
    if (pf) STG(16384, bS, u + 2, 0);
    BAR; LGKM0; SCHED0;
    MFMA16(aH, 4, bB);
    if (pf) { VMC(8); } else { VMC(4); }  // drains Ak0(v),Bk0(v)
    BAR;

    // ---- ph4: v kk0 mL (8 reads); stage Ak1(u+2) ----
    RD_A(aL, 1, 0, 0); RD_B(bA, 1, 0);
    if (pf) STG(8192, aS, u + 2, 1);
    BAR; LGKM0; SCHED0;
    MFMA16(aL, 0, bA);
    BAR;

    // ---- ph5: v kk0 mH (4 reads); stage Bk1(u+2); drain ----
    RD_A(aH, 1, 0, 64);
    if (pf) STG(24576, bS, u + 2, 1);
    BAR; LGKM0; SCHED0;
    MFMA16(aH, 4, bA);
    if (pf) { VMC(8); } else { VMC(0); }  // drains Ak1(v),Bk1(v)
    BAR;

    // ---- ph6: v kk1 mL (8 reads); stage Ak0(v+2) ----
    RD_A(aL, 1, 1, 0); RD_B(bB, 1, 1);
    if (pf) STG(0, aS, v + 2, 0);
    BAR; LGKM0; SCHED0;
    MFMA16(aL, 0, bB);
    BAR;

    // ---- ph7: v kk1 mH (4 reads); stage Bk0(v+2); drain ----
    RD_A(aH, 1, 1, 64);
    if (pf) STG(16384, bS, v + 2, 0);
    BAR; LGKM0; SCHED0;
    MFMA16(aH, 4, bB);
    if (pf) { VMC(8); }  // drains Ak0(u+2),Bk0(u+2)
    BAR;
  }
#undef STG
#undef RD_A
#undef RD_B
#undef MFMA16
#undef BAR
#undef LGKM0
#undef SCHED0
#undef VMC

  // ---- epilogue: C/D layout col = lane&15, row = (lane>>4)*4 + j ----
#pragma unroll
  for (int n = 0; n < 4; ++n) {
    const int col = bcol + wn * 64 + n * 16 + fr;
    const float bb = bias[col];
#pragma unroll
    for (int m = 0; m < 8; ++m) {
      const int row0 = brow + wm * 128 + m * 16 + hi * 4;
#pragma unroll
      for (int j = 0; j < 4; ++j)
        C[(size_t)(row0 + j) * N_DIM + col] = acc[m][n][j] + bb;
    }
  }
}

// ---- fallback (only if ws too small): fp32 LDS-tiled GEMM ----
__global__ __launch_bounds__(256) void k_gemm_f32(
    const float* __restrict__ A, const float* __restrict__ W,
    const float* __restrict__ bias, float* __restrict__ C) {
  __shared__ float As[64][17];
  __shared__ float Ws[16][64];
  const int tid = threadIdx.x;
  const int tx = tid & 15, ty = tid >> 4;
  const int brow = blockIdx.y * 64, bcol = blockIdx.x * 64;
  float acc[4][4] = {};
  for (int ks = 0; ks < K_DIM; ks += 16) {
    {
      const int m = tid >> 2, k = (tid & 3) * 4;
      f32x4 v = *(const f32x4*)&A[(size_t)(brow + m) * K_DIM + ks + k];
      As[m][k] = v[0]; As[m][k + 1] = v[1]; As[m][k + 2] = v[2]; As[m][k + 3] = v[3];
    }
    {
      const int k = tid >> 4, n = (tid & 15) * 4;
      *(f32x4*)&Ws[k][n] = *(const f32x4*)&W[(size_t)(ks + k) * N_DIM + bcol + n];
    }
    __syncthreads();
#pragma unroll
    for (int k = 0; k < 16; ++k) {
      float av[4], bv[4];
#pragma unroll
      for (int i = 0; i < 4; ++i) av[i] = As[ty * 4 + i][k];
#pragma unroll
      for (int j = 0; j < 4; ++j) bv[j] = Ws[k][tx * 4 + j];
#pragma unroll
      for (int i = 0; i < 4; ++i)
#pragma unroll
        for (int j = 0; j < 4; ++j) acc[i][j] += av[i] * bv[j];
    }
    __syncthreads();
  }
#pragma unroll
  for (int i = 0; i < 4; ++i) {
    const int row = brow + ty * 4 + i;
#pragma unroll
    for (int j = 0; j < 4; ++j) {
      const int col = bcol + tx * 4 + j;
      C[(size_t)row * N_DIM + col] = acc[i][j] + bias[col];
    }
  }
}

extern "C" void kernel_launch(void* const* d_in, const int* in_sizes, int n_in,
                              void* d_out, int out_size, void* d_ws, size_t ws_size,
                              hipStream_t stream) {
  const float* inp = (const float*)d_in[0];   // [16384, 4096]
  const float* w = (const float*)d_in[1];     // [4096, 8192]
  const float* bias = (const float*)d_in[2];  // [8192]
  float* out = (float*)d_out;                 // [16384, 8192]

  const size_t needA = (size_t)M_DIM * K_DIM * sizeof(unsigned short);  // 128 MB
  const size_t needW = (size_t)N_DIM * K_DIM * sizeof(unsigned short);  // 64 MB

  if (ws_size >= needA + needW) {
    unsigned short* Abf = (unsigned short*)d_ws;
    unsigned short* Wtb = (unsigned short*)((char*)d_ws + needA);
    k_convert_a<<<2048, 256, 0, stream>>>(inp, Abf);
    k_convert_w_t<<<dim3(N_DIM / 64, K_DIM / 64), 256, 0, stream>>>(w, Wtb);
    k_gemm_8ph<<<(M_DIM / 256) * (N_DIM / 256), 512, 0, stream>>>(Abf, Wtb, bias, out);
  } else {
    k_gemm_f32<<<dim3(N_DIM / 64, M_DIM / 64), 256, 0, stream>>>(inp, w, bias, out);
  }
}

// Round 6
// 1241.491 us; speedup vs baseline: 1.0142x; 1.0001x over previous
//
#include <hip/hip_runtime.h>
#include <hip/hip_bf16.h>

#define M_DIM 16384
#define N_DIM 8192
#define K_DIM 4096
#define NT (K_DIM / 64)  // 64 K-tiles, 32 groups of 2

typedef __attribute__((ext_vector_type(4))) float f32x4;
typedef __attribute__((ext_vector_type(8))) __bf16 bf16x8;
typedef __attribute__((ext_vector_type(4))) unsigned short u16x4;

static __device__ __forceinline__ unsigned short f2bf(float f) {
  __bf16 h = (__bf16)f;
  return __builtin_bit_cast(unsigned short, h);
}

static __device__ __forceinline__ void gl_lds16(const unsigned short* g, unsigned short* l) {
  __builtin_amdgcn_global_load_lds(
      (const __attribute__((address_space(1))) unsigned int*)g,
      (__attribute__((address_space(3))) unsigned int*)l, 16, 0, 0);
}

// ---- prep: A [M][K] f32 -> bf16 (same layout) ----
__global__ void k_convert_a(const float* __restrict__ a, unsigned short* __restrict__ o) {
  const size_t n8 = (size_t)M_DIM * K_DIM / 8;
  for (size_t i = (size_t)blockIdx.x * blockDim.x + threadIdx.x; i < n8;
       i += (size_t)gridDim.x * blockDim.x) {
    const f32x4* p = (const f32x4*)(a + i * 8);
    f32x4 v0 = p[0];
    f32x4 v1 = p[1];
    u16x4 r0, r1;
#pragma unroll
    for (int j = 0; j < 4; ++j) { r0[j] = f2bf(v0[j]); r1[j] = f2bf(v1[j]); }
    *(u16x4*)(o + i * 8) = r0;
    *(u16x4*)(o + i * 8 + 4) = r1;
  }
}

// ---- prep: W [K][N] f32 -> Wt [N][K] bf16 (transpose + convert) ----
__global__ void k_convert_w_t(const float* __restrict__ w, unsigned short* __restrict__ wt) {
  __shared__ float tile[64][65];
  const int bk = blockIdx.y * 64;
  const int bn = blockIdx.x * 64;
  const int t = threadIdx.x;  // 256
  const int c4 = (t & 15) * 4;
  const int r = t >> 4;
#pragma unroll
  for (int p = 0; p < 4; ++p) {
    const int row = r + p * 16;
    f32x4 v = *(const f32x4*)&w[(size_t)(bk + row) * N_DIM + bn + c4];
    tile[row][c4 + 0] = v[0];
    tile[row][c4 + 1] = v[1];
    tile[row][c4 + 2] = v[2];
    tile[row][c4 + 3] = v[3];
  }
  __syncthreads();
#pragma unroll
  for (int p = 0; p < 4; ++p) {
    const int c = r + p * 16;
    u16x4 o;
#pragma unroll
    for (int j = 0; j < 4; ++j) o[j] = f2bf(tile[c4 + j][c]);
    *(u16x4*)&wt[(size_t)(bn + c) * K_DIM + bk + c4] = o;
  }
}

// ---- main GEMM: 256x256, BK=64, 8-phase/2-K-tile, PIPELINED ds_reads ----
// LDS 128KB = 2 tile-buffers x {Ak0,Ak1,Bk0,Bk1} x 16KB (256 rows x 32 k).
// Phase p: issue reads(p+1) into alt reg set; 1 stage; lgkmcnt(N just issued)
// -> waits reads(p); sched_barrier; 16 MFMA on set read in p-1; [vmcnt(6) at
// even phases]; ONE s_barrier. LDS pipe overlaps matrix pipe every phase.
// Stage slots: ph0:Ak1(v) ph1:Bk1(v) ph2:Ak0(u+2) ph3:Bk0(u+2)
//              ph4:Ak1(u+2) ph5:Bk1(u+2) ph6:Ak0(v+2) ph7:Bk0(v+2)
// vmcnt(6) end of even phases: drained stage is 3 phases old. WAR: every
// re-stage >=2 barriers after victim's lgkm-fenced reads (ledger-checked).
__global__ __launch_bounds__(512, 2) void k_gemm_8ph(
    const unsigned short* __restrict__ A, const unsigned short* __restrict__ Bt,
    const float* __restrict__ bias, float* __restrict__ C) {
  __shared__ __align__(16) unsigned short S[65536];  // 128 KB

  const int tid = threadIdx.x;
  const int lane = tid & 63;
  const int wave = tid >> 6;  // 0..7
  const int wm = wave >> 2;   // 0..1 -> 128-row half
  const int wn = wave & 3;    // 0..3 -> 64-col block
  const int fr = lane & 15;
  const int hi = lane >> 4;   // 0..3

  // T1: XCD-aware bijective swizzle (2048 blocks, %8==0)
  const int bid = blockIdx.x;
  const int swz = (bid & 7) * 256 + (bid >> 3);
  const int local = swz & 255;
  const int tm = local & 63;
  const int tn = (swz >> 8) * 4 + (local >> 6);
  const int brow = tm * 256;
  const int bcol = tn * 256;

  // staging source: row = tid>>2 (+128 for 2nd gl_lds), dest granule tid&3,
  // source granule = dest ^ ((row>>1)&3) = dest ^ ((tid>>3)&3).
  const int srow2 = tid >> 2;
  const int sgel = ((tid & 3) ^ ((tid >> 3) & 3)) * 8;
  const unsigned short* aS = A + (size_t)(brow + srow2) * K_DIM + sgel;
  const unsigned short* bS = Bt + (size_t)(bcol + srow2) * K_DIM + sgel;

#define STG(reg, srcp, tt, kh)                                        \
  do {                                                                \
    unsigned short* d_ = S + ((tt)&1) * 32768 + (reg) + tid * 8;      \
    const unsigned short* g_ = (srcp) + (size_t)(tt)*64 + (kh)*32;    \
    gl_lds16(g_, d_);                                                 \
    gl_lds16(g_ + (size_t)128 * K_DIM, d_ + 4096);                    \
  } while (0)

  // frag-read swizzled granule: phys = hi ^ ((row>>1)&3); row bases are
  // multiples of 16 so (row>>1)&3 == (fr>>1)&3 (lane-constant).
  const int swk = ((hi ^ ((fr >> 1) & 3)) * 8);
  const unsigned short* SA = S + (wm * 128 + fr) * 32 + swk;
  const unsigned short* SB = S + 16384 + (wn * 64 + fr) * 32 + swk;

#define RD_A(dst, X, h, mb)                                                       \
  _Pragma("unroll") for (int m_ = 0; m_ < 4; ++m_)                                \
      dst[m_] = *(const bf16x8*)(SA + (X)*32768 + (h)*8192 + ((mb) + m_ * 16) * 32);
#define RD_B(dst, X, h)                                                           \
  _Pragma("unroll") for (int n_ = 0; n_ < 4; ++n_)                                \
      dst[n_] = *(const bf16x8*)(SB + (X)*32768 + (h)*8192 + n_ * 512);

  f32x4 acc[8][4] = {};

#define BAR __builtin_amdgcn_s_barrier()
#define SCHED0 __builtin_amdgcn_sched_barrier(0)
#define WAITL(n) asm volatile("s_waitcnt lgkmcnt(" #n ")" ::: "memory")
#define VMC(n) asm volatile("s_waitcnt vmcnt(" #n ")" ::: "memory")
#define MFMA16(AV, MB, BV)                                                            \
  __builtin_amdgcn_s_setprio(1);                                                      \
  _Pragma("unroll") for (int m_ = 0; m_ < 4; ++m_)                                    \
      _Pragma("unroll") for (int n_ = 0; n_ < 4; ++n_)                                \
          acc[(MB) + m_][n_] = __builtin_amdgcn_mfma_f32_16x16x32_bf16(               \
              AV[m_], BV[n_], acc[(MB) + m_][n_], 0, 0, 0);                           \
  __builtin_amdgcn_s_setprio(0)

  bf16x8 aX[4], aY[4], bX[4], bY[4];

  // ---- prologue: tile0 all 4 + {Ak0,Bk0}(1); drain tile0 k0; reads for ph0 ----
  STG(0, aS, 0, 0);      // Ak0(0)
  STG(16384, bS, 0, 0);  // Bk0(0)
  STG(8192, aS, 0, 1);   // Ak1(0)
  STG(24576, bS, 0, 1);  // Bk1(0)
  STG(0, aS, 1, 0);      // Ak0(1)
  STG(16384, bS, 1, 0);  // Bk0(1)
  VMC(8);                // Ak0(0),Bk0(0) complete; 8 loads outstanding
  BAR;
  RD_A(aX, 0, 0, 0);     // u=0 kk0 mL
  RD_B(bX, 0, 0);        // u=0 kk0 B

  const int NTH = NT / 2;
  for (int it = 0; it < NTH; ++it) {
    const int u = 2 * it, v = u + 1;
    const bool pf = (it < NTH - 1);

    // ---- ph0: load(u kk0 mH); stage Ak1(v); MFMA u kk0 mL ----
    RD_A(aY, 0, 0, 64);
    STG(8192, aS, v, 1);
    WAITL(4); SCHED0;
    MFMA16(aX, 0, bX);
    VMC(6);
    BAR;

    // ---- ph1: load(u kk1 mL + B u kk1); stage Bk1(v); MFMA u kk0 mH ----
    RD_A(aX, 0, 1, 0); RD_B(bY, 0, 1);
    STG(24576, bS, v, 1);
    WAITL(8); SCHED0;
    MFMA16(aY, 4, bX);
    BAR;

    // ---- ph2: load(u kk1 mH); stage Ak0(u+2); MFMA u kk1 mL ----
    RD_A(aY, 0, 1, 64);
    if (pf) STG(0, aS, u + 2, 0);
    WAITL(4); SCHED0;
    MFMA16(aX, 0, bY);
    if (pf) { VMC(6); } else { VMC(4); }
    BAR;

    // ---- ph3: load(v kk0 mL + B v kk0); stage Bk0(u+2); MFMA u kk1 mH ----
    RD_A(aX, 1, 0, 0); RD_B(bX, 1, 0);
    if (pf) STG(16384, bS, u + 2, 0);
    WAITL(8); SCHED0;
    MFMA16(aY, 4, bY);
    BAR;

    // ---- ph4: load(v kk0 mH); stage Ak1(u+2); MFMA v kk0 mL ----
    RD_A(aY, 1, 0, 64);
    if (pf) STG(8192, aS, u + 2, 1);
    WAITL(4); SCHED0;
    MFMA16(aX, 0, bX);
    if (pf) { VMC(6); } else { VMC(0); }
    BAR;

    // ---- ph5: load(v kk1 mL + B v kk1); stage Bk1(u+2); MFMA v kk0 mH ----
    RD_A(aX, 1, 1, 0); RD_B(bY, 1, 1);
    if (pf) STG(24576, bS, u + 2, 1);
    WAITL(8); SCHED0;
    MFMA16(aY, 4, bX);
    BAR;

    // ---- ph6: load(v kk1 mH); stage Ak0(v+2); MFMA v kk1 mL ----
    RD_A(aY, 1, 1, 64);
    if (pf) STG(0, aS, v + 2, 0);
    WAITL(4); SCHED0;
    MFMA16(aX, 0, bY);
    if (pf) { VMC(6); }
    BAR;

    // ---- ph7: load(next-u kk0 mL + B); stage Bk0(v+2); MFMA v kk1 mH ----
    if (pf) { RD_A(aX, 0, 0, 0); RD_B(bX, 0, 0); }
    if (pf) STG(16384, bS, v + 2, 0);
    if (pf) { WAITL(8); } else { WAITL(0); }
    SCHED0;
    MFMA16(aY, 4, bY);
    BAR;
  }
#undef STG
#undef RD_A
#undef RD_B
#undef MFMA16
#undef BAR
#undef SCHED0
#undef WAITL
#undef VMC

  // ---- epilogue: C/D layout col = lane&15, row = (lane>>4)*4 + j ----
#pragma unroll
  for (int n = 0; n < 4; ++n) {
    const int col = bcol + wn * 64 + n * 16 + fr;
    const float bb = bias[col];
#pragma unroll
    for (int m = 0; m < 8; ++m) {
      const int row0 = brow + wm * 128 + m * 16 + hi * 4;
#pragma unroll
      for (int j = 0; j < 4; ++j)
        C[(size_t)(row0 + j) * N_DIM + col] = acc[m][n][j] + bb;
    }
  }
}

// ---- fallback (only if ws too small): fp32 LDS-tiled GEMM ----
__global__ __launch_bounds__(256) void k_gemm_f32(
    const float* __restrict__ A, const float* __restrict__ W,
    const float* __restrict__ bias, float* __restrict__ C) {
  __shared__ float As[64][17];
  __shared__ float Ws[16][64];
  const int tid = threadIdx.x;
  const int tx = tid & 15, ty = tid >> 4;
  const int brow = blockIdx.y * 64, bcol = blockIdx.x * 64;
  float acc[4][4] = {};
  for (int ks = 0; ks < K_DIM; ks += 16) {
    {
      const int m = tid >> 2, k = (tid & 3) * 4;
      f32x4 v = *(const f32x4*)&A[(size_t)(brow + m) * K_DIM + ks + k];
      As[m][k] = v[0]; As[m][k + 1] = v[1]; As[m][k + 2] = v[2]; As[m][k + 3] = v[3];
    }
    {
      const int k = tid >> 4, n = (tid & 15) * 4;
      *(f32x4*)&Ws[k][n] = *(const f32x4*)&W[(size_t)(ks + k) * N_DIM + bcol + n];
    }
    __syncthreads();
#pragma unroll
    for (int k = 0; k < 16; ++k) {
      float av[4], bv[4];
#pragma unroll
      for (int i = 0; i < 4; ++i) av[i] = As[ty * 4 + i][k];
#pragma unroll
      for (int j = 0; j < 4; ++j) bv[j] = Ws[k][tx * 4 + j];
#pragma unroll
      for (int i = 0; i < 4; ++i)
#pragma unroll
        for (int j = 0; j < 4; ++j) acc[i][j] += av[i] * bv[j];
    }
    __syncthreads();
  }
#pragma unroll
  for (int i = 0; i < 4; ++i) {
    const int row = brow + ty * 4 + i;
#pragma unroll
    for (int j = 0; j < 4; ++j) {
      const int col = bcol + tx * 4 + j;
      C[(size_t)row * N_DIM + col] = acc[i][j] + bias[col];
    }
  }
}

extern "C" void kernel_launch(void* const* d_in, const int* in_sizes, int n_in,
                              void* d_out, int out_size, void* d_ws, size_t ws_size,
                              hipStream_t stream) {
  const float* inp = (const float*)d_in[0];   // [16384, 4096]
  const float* w = (const float*)d_in[1];     // [4096, 8192]
  const float* bias = (const float*)d_in[2];  // [8192]
  float* out = (float*)d_out;                 // [16384, 8192]

  const size_t needA = (size_t)M_DIM * K_DIM * sizeof(unsigned short);  // 128 MB
  const size_t needW = (size_t)N_DIM * K_DIM * sizeof(unsigned short);  // 64 MB

  if (ws_size >= needA + needW) {
    unsigned short* Abf = (unsigned short*)d_ws;
    unsigned short* Wtb = (unsigned short*)((char*)d_ws + needA);
    k_convert_a<<<2048, 256, 0, stream>>>(inp, Abf);
    k_convert_w_t<<<dim3(N_DIM / 64, K_DIM / 64), 256, 0, stream>>>(w, Wtb);
    k_gemm_8ph<<<(M_DIM / 256) * (N_DIM / 256), 512, 0, stream>>>(Abf, Wtb, bias, out);
  } else {
    k_gemm_f32<<<dim3(N_DIM / 64, M_DIM / 64), 256, 0, stream>>>(inp, w, bias, out);
  }
}